// Round 11
// baseline (1342.966 us; speedup 1.0000x reference)
//
#include <hip/hip_runtime.h>
#include <math.h>

// ---- problem constants (from reference) ----
#define T_TOT  200000
#define EE     500
#define EI     100
#define SUBN   20
#define NCH    40      // 2*SUB
#define HIDN   20
#define BNO    34
#define TM     101     // basis kernel length
#define TNO    50      // history length / half kernel
#define HBNO   18
#define TT1    256     // t-tile for conv2/output kernels
#define EPSF   2e-5f   // sound margin for interval determinations
#define NTAP   58      // 34 G-taps + 24 edge-correction taps
#define CPT    12      // coefficient slots per tap (10 used, 48B stride)

// padded syn row: [64 zeros][T][256 zeros]
#define PADL   64
#define PADR   256
#define SROW   (PADL + T_TOT + PADR)   // 200320

// prefiltered G row: G_s[tau] at [s*GROW + tau+50], tau in [-50, T+61]
#define GROW   (T_TOT + 112)           // 200112

// conv1 tiling: 512 t per block, 128 threads (2 waves), 8 t per lane
#define C1TB   512
#define GW2    (C1TB + 99)     // 611
#define SW2    (C1TB + 124)    // 636
#define CW     (2 * NTAP * CPT)   // 1392 coefficient floats per s

// relax tiling
#define RTILE  512
#define RHALO  64
#define RRND   4
#define NT2    ((T_TOT + RTILE - 1) / RTILE)   // 391

// ======================= setup: assignments, small kernels, basis ============
__global__ void k_setup(const float* __restrict__ Ce, const float* __restrict__ Ci,
                        const float* __restrict__ Wh, const float* __restrict__ Wspk,
                        const float* __restrict__ Tau,
                        int* __restrict__ ae, int* __restrict__ ai,
                        float* __restrict__ hkpos, float* __restrict__ hkneg,
                        float* __restrict__ spkk, float* __restrict__ gtap,
                        double* __restrict__ hkd, double* __restrict__ basisd)
{
    int tid = threadIdx.x;  // block 1024
    if (tid < EE) {
        int a = 0;
        for (int s = 0; s < SUBN; ++s) if (Ce[s * EE + tid] > 0.5f) a = s;
        ae[tid] = a;
    } else if (tid < EE + EI) {
        int e = tid - EE; int a = 0;
        for (int s = 0; s < SUBN; ++s) if (Ci[s * EI + e] > 0.5f) a = s;
        ai[e] = a;
    } else if (tid < 664) {
        // hk_r[j] = hist_kern[TNO - j], j in [1,TNO]; zero-fill rest of 64
        int j = tid - 600;
        double hk = 0.0;
        if (j >= 1 && j <= TNO) {
            int i = TNO - j;
            for (int b = 0; b < HBNO; ++b) {
                double d = (double)i - 3.0 * (double)b;
                hk += (double)Wh[b] * exp(-d * d / 3.0);
            }
        }
        hkd[j] = hk;
        hkpos[j] = (float)fmax(hk, 0.0);
        hkneg[j] = (float)fmin(hk, 0.0);
    } else if (tid < 728) {
        int m = tid - 664; float v = 0.f;
        if (m < TNO) {
            double tau2 = (double)Tau[0] * (double)Tau[0];
            double tt = (double)m / tau2;
            v = (float)(tt * exp(-tt) * (double)Wspk[0] * (double)Wspk[0]);
        }
        spkk[m] = v;
    } else if (tid < 753) {
        int j = tid - 740;                       // j in [-12, 12]
        gtap[tid - 728] = (float)exp(-(double)(j * j) / 3.0);
    }
    // Gaussian basis table (fp64) for kern4 construction
    for (int idx = tid; idx < BNO * TM; idx += blockDim.x) {
        int b = idx / TM, k = idx % TM;
        double d = (double)k - 3.0 * (double)b;
        basisd[idx] = exp(-d * d / 3.0);
    }
}

// ======================= prep: kern4, wave-packed coefficients, pads =========
// cmerged layout: [s][hgrp(2)][tap(58)][12]; slot f<10 -> h = hgrp*10+f.
// tap<34: w1[h,s,tap]; tap>=34 (mi=tap-34): NEGATED edge-correction coef.
__global__ void k_prep(const float* __restrict__ w1, const float* __restrict__ w4,
                       const double* __restrict__ basisd,
                       float* __restrict__ kern4, float* __restrict__ cmerged,
                       float* __restrict__ syn)
{
    int idx = blockIdx.x * 256 + threadIdx.x;
    if (idx < HIDN * TM) {
        int h = idx % HIDN, k = idx / HIDN;
        double acc = 0.0;
        for (int b = 0; b < BNO; ++b) acc += (double)w4[h * BNO + b] * basisd[b * TM + k];
        kern4[k * HIDN + h] = (float)acc;        // [k][h] layout
    } else if (idx < 2020 + NCH * CW) {
        int j = idx - 2020;
        int f = j % CPT, tap = (j / CPT) % NTAP, hg = (j / (CPT * NTAP)) & 1, s = j / CW;
        float val = 0.f;
        if (f < 10) {
            int h = hg * 10 + f;
            if (tap < BNO) {
                val = w1[(h * NCH + s) * BNO + tap];
            } else {
                int mi = tap - BNO;
                int m = (mi < 12) ? (mi - 62) : (mi + 39);
                double acc = 0.0;
                for (int b = 0; b < BNO; ++b) {
                    int jj = m + 50 - 3 * b;     // Gaussian tap our G includes
                    if (jj >= -12 && jj <= 12)
                        acc += (double)w1[(h * NCH + s) * BNO + b] * exp(-(double)(jj * jj) / 3.0);
                }
                val = -(float)acc;               // pre-negated
            }
        }
        cmerged[j] = val;
    } else if (idx < 2020 + NCH * CW + NCH * (PADL + PADR)) {
        int j = idx - (2020 + NCH * CW);
        int r = j / (PADL + PADR), c = j % (PADL + PADR);
        int off = (c < PADL) ? c : (PADL + T_TOT + (c - PADL));
        syn[(size_t)r * SROW + off] = 0.f;
    }
}

// ======================= synapse -> subunit routing (float4, 2-way ILP) ======
__global__ __launch_bounds__(256) void k_route(const float* __restrict__ Se,
                                               const float* __restrict__ Si,
                                               const int* __restrict__ ae,
                                               const int* __restrict__ ai,
                                               float* __restrict__ syn)
{
    __shared__ float acc[NCH * 64];
    __shared__ int sae[EE];
    __shared__ int sai[EI];
    int tid = threadIdx.x;
    for (int i = tid; i < NCH * 64; i += 256) acc[i] = 0.f;
    for (int i = tid; i < EE; i += 256) sae[i] = ae[i];
    for (int i = tid; i < EI; i += 256) sai[i] = ai[i];
    __syncthreads();
    int t0 = blockIdx.x * 64;              // T divisible by 64
    int lane = tid & 63, grp = tid >> 6;
    for (int ec = 0; ec < 2; ++ec) {
        int ev = ec * 64 + lane;           // float4 index; 125 cover 500 floats
        if (ev < EE / 4) {
            int e = 4 * ev;
            int a0 = sae[e], a1 = sae[e + 1], a2 = sae[e + 2], a3 = sae[e + 3];
            for (int ts = grp; ts < 64; ts += 8) {
                float4 v1 = *(const float4*)(Se + (size_t)(t0 + ts) * EE + e);
                float4 v2 = *(const float4*)(Se + (size_t)(t0 + ts + 4) * EE + e);
                if (v1.x != 0.f) atomicAdd(&acc[a0 * 64 + ts], v1.x);
                if (v1.y != 0.f) atomicAdd(&acc[a1 * 64 + ts], v1.y);
                if (v1.z != 0.f) atomicAdd(&acc[a2 * 64 + ts], v1.z);
                if (v1.w != 0.f) atomicAdd(&acc[a3 * 64 + ts], v1.w);
                if (v2.x != 0.f) atomicAdd(&acc[a0 * 64 + ts + 4], v2.x);
                if (v2.y != 0.f) atomicAdd(&acc[a1 * 64 + ts + 4], v2.y);
                if (v2.z != 0.f) atomicAdd(&acc[a2 * 64 + ts + 4], v2.z);
                if (v2.w != 0.f) atomicAdd(&acc[a3 * 64 + ts + 4], v2.w);
            }
        }
    }
    {
        int ev = lane;                     // 25 cover 100 floats
        if (ev < EI / 4) {
            int e = 4 * ev;
            int a0 = sai[e] + SUBN, a1 = sai[e + 1] + SUBN, a2 = sai[e + 2] + SUBN, a3 = sai[e + 3] + SUBN;
            for (int ts = grp; ts < 64; ts += 8) {
                float4 v1 = *(const float4*)(Si + (size_t)(t0 + ts) * EI + e);
                float4 v2 = *(const float4*)(Si + (size_t)(t0 + ts + 4) * EI + e);
                if (v1.x != 0.f) atomicAdd(&acc[a0 * 64 + ts], v1.x);
                if (v1.y != 0.f) atomicAdd(&acc[a1 * 64 + ts], v1.y);
                if (v1.z != 0.f) atomicAdd(&acc[a2 * 64 + ts], v1.z);
                if (v1.w != 0.f) atomicAdd(&acc[a3 * 64 + ts], v1.w);
                if (v2.x != 0.f) atomicAdd(&acc[a0 * 64 + ts + 4], v2.x);
                if (v2.y != 0.f) atomicAdd(&acc[a1 * 64 + ts + 4], v2.y);
                if (v2.z != 0.f) atomicAdd(&acc[a2 * 64 + ts + 4], v2.z);
                if (v2.w != 0.f) atomicAdd(&acc[a3 * 64 + ts + 4], v2.w);
            }
        }
    }
    __syncthreads();
    for (int i = tid; i < NCH * 64; i += 256) {
        int s = i >> 6, ts = i & 63;
        syn[(size_t)s * SROW + PADL + t0 + ts] = acc[i];
    }
}

// ======================= Gaussian prefilter: G_s = g (*) syn_s ===============
__global__ __launch_bounds__(256) void k_prefilt(const float* __restrict__ syn,
                                                 const float* __restrict__ gtap,
                                                 float* __restrict__ G)
{
    int gi = blockIdx.x * 256 + threadIdx.x;     // gridDim.y = s
    if (gi >= GROW) return;
    const float* sp = syn + (size_t)blockIdx.y * SROW + PADL + (gi - 50);
    double a = 0.0;
#pragma unroll
    for (int j = -12; j <= 12; ++j)
        a += (double)gtap[j + 12] * (double)sp[j];
    G[(size_t)blockIdx.y * GROW + gi] = (float)a;
}

// ======================= conv1: 8t/lane, LDS coef broadcasts =================
// Block = 128 thr (2 waves); wave w = h-group w*10..+9; lane owns t = t0 +
// lane + 64k, k=0..7 (stride-64 reads: conflict-free, ds_read2st64-mergeable).
// Coefficients staged in LDS, read as wave-uniform broadcasts: 30 LDS-cyc per
// tap amortized over 80 lane-FMAs. FMA order per (h,t): s asc, tap asc --
// identical to R4-R10 -> bitwise-identical out1.
__global__ __launch_bounds__(128) void k_conv1w(const float* __restrict__ G,
                                                const float* __restrict__ syn,
                                                const float* __restrict__ cmerged,
                                                float* __restrict__ out1)
{
    __shared__ __align__(16) float sg[2][GW2];
    __shared__ __align__(16) float ss[2][SW2];
    __shared__ __align__(16) float sc[2][CW];
    int tid = threadIdx.x;
    int hg = tid >> 6;                   // wave 0: h 0..9, wave 1: h 10..19
    int lane = tid & 63;
    int t0 = blockIdx.x * C1TB;

    {   // stage s=0 into buffer 0
        const float* Gp = G + t0;
        const float* sp = syn + PADL + t0 - 62;
        for (int i = tid; i < GW2; i += 128) sg[0][i] = (t0 + i < GROW) ? Gp[i] : 0.f;
        for (int i = tid; i < SW2; i += 128) ss[0][i] = sp[i];
        for (int i = tid; i < CW; i += 128) sc[0][i] = cmerged[i];
    }

    float acc[10][8];
#pragma unroll
    for (int hh = 0; hh < 10; ++hh)
#pragma unroll
        for (int k = 0; k < 8; ++k) acc[hh][k] = 0.f;

    for (int s = 0; s < NCH; ++s) {
        __syncthreads();                 // buf[s&1] staged & prior reads done
        int cb = s & 1, nb = cb ^ 1;
        if (s + 1 < NCH) {               // prefetch next s
            const float* Gp = G + (size_t)(s + 1) * GROW + t0;
            const float* sp = syn + (size_t)(s + 1) * SROW + PADL + t0 - 62;
            const float* cp = cmerged + (size_t)(s + 1) * CW;
            for (int i = tid; i < GW2; i += 128) sg[nb][i] = (t0 + i < GROW) ? Gp[i] : 0.f;
            for (int i = tid; i < SW2; i += 128) ss[nb][i] = sp[i];
            for (int i = tid; i < CW; i += 128) sc[nb][i] = cp[i];
        }
        const float* sgc = sg[cb] + lane;
        const float* ssc = ss[cb] + lane;
        const float* cc = sc[cb] + hg * (NTAP * CPT);
#pragma unroll 2
        for (int b = 0; b < BNO; ++b) {
            const float* cp = cc + b * CPT;          // 48B stride: 16B-aligned
            float4 c0 = *(const float4*)cp;          // wave-uniform broadcasts
            float4 c1 = *(const float4*)(cp + 4);
            float2 c2 = *(const float2*)(cp + 8);
            float v[8];
#pragma unroll
            for (int k = 0; k < 8; ++k) v[k] = sgc[3 * b + 64 * k];
#pragma unroll
            for (int k = 0; k < 8; ++k) {
                acc[0][k] = fmaf(c0.x, v[k], acc[0][k]);
                acc[1][k] = fmaf(c0.y, v[k], acc[1][k]);
                acc[2][k] = fmaf(c0.z, v[k], acc[2][k]);
                acc[3][k] = fmaf(c0.w, v[k], acc[3][k]);
                acc[4][k] = fmaf(c1.x, v[k], acc[4][k]);
                acc[5][k] = fmaf(c1.y, v[k], acc[5][k]);
                acc[6][k] = fmaf(c1.z, v[k], acc[6][k]);
                acc[7][k] = fmaf(c1.w, v[k], acc[7][k]);
                acc[8][k] = fmaf(c2.x, v[k], acc[8][k]);
                acc[9][k] = fmaf(c2.y, v[k], acc[9][k]);
            }
        }
#pragma unroll 2
        for (int mi = 0; mi < 24; ++mi) {
            int doff = (mi < 12) ? mi : (mi + 101);  // syn_s[t+mi-62] | [t+mi+39]
            const float* cp = cc + (BNO + mi) * CPT;
            float4 c0 = *(const float4*)cp;          // pre-negated coefficients
            float4 c1 = *(const float4*)(cp + 4);
            float2 c2 = *(const float2*)(cp + 8);
            float v[8];
#pragma unroll
            for (int k = 0; k < 8; ++k) v[k] = ssc[doff + 64 * k];
#pragma unroll
            for (int k = 0; k < 8; ++k) {
                acc[0][k] = fmaf(c0.x, v[k], acc[0][k]);
                acc[1][k] = fmaf(c0.y, v[k], acc[1][k]);
                acc[2][k] = fmaf(c0.z, v[k], acc[2][k]);
                acc[3][k] = fmaf(c0.w, v[k], acc[3][k]);
                acc[4][k] = fmaf(c1.x, v[k], acc[4][k]);
                acc[5][k] = fmaf(c1.y, v[k], acc[5][k]);
                acc[6][k] = fmaf(c1.z, v[k], acc[6][k]);
                acc[7][k] = fmaf(c1.w, v[k], acc[7][k]);
                acc[8][k] = fmaf(c2.x, v[k], acc[8][k]);
                acc[9][k] = fmaf(c2.y, v[k], acc[9][k]);
            }
        }
    }
    int tb = t0 + lane;
#pragma unroll
    for (int hh = 0; hh < 10; ++hh) {
        int h = hg * 10 + hh;
#pragma unroll
        for (int k = 0; k < 8; ++k) {
            int t = tb + 64 * k;
            if (t < T_TOT) {
                float o = acc[hh][k];
                out1[(size_t)h * T_TOT + t] = (o > 0.f) ? o : 0.01f * o;
            }
        }
    }
}

// ======================= conv2 (fp64 acc) + logit threshold + state init =====
__global__ __launch_bounds__(256) void k_conv2(const float* __restrict__ out1,
                                               const float* __restrict__ kern4,
                                               const float* __restrict__ Theta,
                                               const float* __restrict__ u,
                                               double* __restrict__ xd,
                                               double* __restrict__ thrd,
                                               float* __restrict__ thr32,
                                               float* __restrict__ blo,
                                               float* __restrict__ bhi)
{
    __shared__ float s1[HIDN * (TT1 + 100)];    // 28,480 B
    int tid = threadIdx.x;
    int t0 = blockIdx.x * TT1;
    for (int i = tid; i < HIDN * (TT1 + 100); i += 256) {
        int h = i / (TT1 + 100), x = i % (TT1 + 100);
        int g = t0 + x - TNO;
        s1[i] = (g >= 0 && g < T_TOT) ? out1[(size_t)h * T_TOT + g] : 0.f;
    }
    __syncthreads();
    int t = t0 + tid;
    if (t >= T_TOT) return;
    double acc = 0.0;
    for (int k = 0; k < TM; ++k) {
        const float* kp = kern4 + k * HIDN;
#pragma unroll
        for (int h = 0; h < HIDN; ++h)
            acc = fma((double)s1[h * (TT1 + 100) + tid + k], (double)kp[h], acc);
    }
    double x = acc + (double)Theta[0];
    double uu = (double)u[t];
    // spike  <=>  u < sigmoid(x + a)  <=>  a > logit(u) - x
    double th = (log(uu) - log1p(-uu)) - x;     // u==0 -> -inf -> always spike (correct)
    xd[t] = x; thrd[t] = th; thr32[t] = (float)th;
    // interval init (index = t + TNO): unknown everywhere, pads zero
    blo[t + TNO] = 0.f;
    bhi[t + TNO] = 1.f;
    if (t < TNO) { blo[t] = 0.f; bhi[t] = 0.f; }
    if (t < 14)  { blo[T_TOT + TNO + t] = 0.f; bhi[T_TOT + TNO + t] = 0.f; }
}

// ======================= sound interval relaxation (+ optional dirty) ========
__global__ __launch_bounds__(256) void k_relax(const float* __restrict__ thr32,
                                               const float* __restrict__ hkpos,
                                               const float* __restrict__ hkneg,
                                               float* __restrict__ blo,
                                               float* __restrict__ bhi,
                                               int wd, int* __restrict__ dirty)
{
    __shared__ float slo[RTILE + RHALO], shi[RTILE + RHALO];
    __shared__ float sth[RTILE + RHALO];
    __shared__ float shp[64], shn[64];
    int tid = threadIdx.x;
    int t0 = blockIdx.x * RTILE;
    for (int i = tid; i < RTILE + RHALO; i += 256) {
        int t = t0 - RHALO + i;
        int g = t + TNO;
        bool ok = (g >= 0 && g < T_TOT + 64);
        slo[i] = ok ? blo[g] : 0.f;
        shi[i] = ok ? bhi[g] : 0.f;
        sth[i] = (t >= 0 && t < T_TOT) ? thr32[t] : 0.f;
    }
    if (tid < 64) { shp[tid] = hkpos[tid]; shn[tid] = hkneg[tid]; }
    __syncthreads();
    for (int r = 0; r < RRND; ++r) {
        for (int i = tid; i < RTILE + RHALO; i += 256) {
            if (i < TNO) continue;                   // needs 50 left neighbors in LDS
            float l = slo[i], h = shi[i];
            if (l == h) continue;
            float lo = 0.f, hi = 0.f;
            for (int j = 1; j <= TNO; ++j) {
                float bl = slo[i - j], bh = shi[i - j];
                float hp = shp[j], hn = shn[j];
                lo = fmaf(hp, bl, lo); lo = fmaf(hn, bh, lo);
                hi = fmaf(hp, bh, hi); hi = fmaf(hn, bl, hi);
            }
            float th = sth[i];
            if (lo > th + EPSF)      slo[i] = 1.f;   // determined spike
            else if (hi < th - EPSF) shi[i] = 0.f;   // determined no-spike
        }
        __syncthreads();
    }
    for (int i = tid; i < RTILE; i += 256) {         // write back interior only
        int t = t0 + i;
        if (t < T_TOT) {
            blo[t + TNO] = slo[RHALO + i];
            bhi[t + TNO] = shi[RHALO + i];
        }
    }
    if (wd) {                                        // final launch: per-tile counts
        int i1 = tid, i2 = tid + 256;
        int u1 = (t0 + i1 < T_TOT) && (slo[RHALO + i1] != shi[RHALO + i1]);
        int u2 = (t0 + i2 < T_TOT) && (slo[RHALO + i2] != shi[RHALO + i2]);
        int c = __syncthreads_count(u1);
        c += __syncthreads_count(u2);
        if (tid == 0) dirty[blockIdx.x] = c;
    }
}

// ======================= compact unknowns + known-history dots (fp64) ========
__global__ __launch_bounds__(512) void k_compact(const float* __restrict__ blo,
                                                 const float* __restrict__ bhi,
                                                 const int* __restrict__ dirty,
                                                 const double* __restrict__ hkd,
                                                 int* __restrict__ list,
                                                 int* __restrict__ utot,
                                                 double* __restrict__ afix)
{
    __shared__ int wsum[8];
    __shared__ int sd[NT2];
    __shared__ int sbase;
    int tid = threadIdx.x;
    for (int i = tid; i < NT2; i += 512) sd[i] = dirty[i];
    int t = blockIdx.x * 512 + tid;
    int unk = (t < T_TOT) && (blo[t + TNO] != bhi[t + TNO]);
    unsigned long long m = __ballot(unk);
    int lane = tid & 63, wv = tid >> 6;
    int lr = __popcll(m & ((1ull << lane) - 1ull));
    if (lane == 0) wsum[wv] = __popcll(m);
    __syncthreads();
    if (tid == 0) {
        int b = 0;
        for (int k = 0; k < (int)blockIdx.x; ++k) b += sd[k];
        sbase = b;
        if (blockIdx.x == 0) {
            int tot = 0;
            for (int k = 0; k < NT2; ++k) tot += sd[k];
            utot[0] = tot;
        }
        int r = 0;
        for (int k = 0; k < 8; ++k) { int c = wsum[k]; wsum[k] = r; r += c; }
    }
    __syncthreads();
    if (unk) {
        int pos = sbase + wsum[wv] + lr;
        list[pos] = t;
        double a = 0.0;
        for (int j = 1; j <= TNO; ++j)
            a += hkd[j] * (double)blo[t - j + TNO];   // unknowns read as 0
        afix[pos] = a;
    }
}

// ======================= chain split + exact resolve (single block) ==========
__global__ __launch_bounds__(1024) void k_chainres(const int* __restrict__ list,
                                                   const double* __restrict__ afix,
                                                   const double* __restrict__ thrd,
                                                   const double* __restrict__ hkd,
                                                   const int* __restrict__ utot,
                                                   int* __restrict__ chead,
                                                   int* __restrict__ bits,
                                                   float* __restrict__ blo,
                                                   float* __restrict__ bhi)
{
    __shared__ double shk[64];
    __shared__ int wcnt[16];
    __shared__ int base_s;
    int tid = threadIdx.x, lane = tid & 63, wv = tid >> 6;
    if (tid < 64) shk[tid] = (tid >= 1 && tid <= TNO) ? hkd[tid] : 0.0;
    if (tid == 0) base_s = 0;
    int U = utot[0];
    __syncthreads();
    for (int b0 = 0; b0 < U; b0 += 1024) {
        int i = b0 + tid;
        int head = 0;
        if (i < U) head = (i == 0) || (list[i] - list[i - 1] > TNO);
        unsigned long long m = __ballot(head);
        int pre = __popcll(m & ((1ull << lane) - 1ull));
        if (lane == 0) wcnt[wv] = __popcll(m);
        __syncthreads();
        int wbase = 0;
        for (int k = 0; k < wv; ++k) wbase += wcnt[k];
        int tot = 0;
        for (int k = 0; k < 16; ++k) tot += wcnt[k];
        if (head) chead[base_s + wbase + pre] = i;
        __syncthreads();
        if (tid == 0) base_s += tot;
        __syncthreads();
    }
    int nch = base_s;
    for (int c = tid; c < nch; c += 1024) {
        int i0 = chead[c];
        int i1 = (c + 1 < nch) ? chead[c + 1] : U;
        for (int i = i0; i < i1; ++i) {
            int t = list[i];
            double a = afix[i];
            for (int k = i - 1; k >= i0; --k) {   // unknown predecessors (same chain)
                int dt = t - list[k];
                if (dt > TNO) break;
                if (bits[k]) a += shk[dt];
            }
            int sb = (a > thrd[t]) ? 1 : 0;
            bits[i] = sb;
            float f = (float)sb;
            blo[t + TNO] = f;
            bhi[t + TNO] = f;
        }
    }
}

// ======================= outputs: spk_filt + prob_out ========================
__global__ __launch_bounds__(256) void k_out(const float* __restrict__ blo,
                                             const float* __restrict__ spkk,
                                             const double* __restrict__ hkd,
                                             const double* __restrict__ xd,
                                             float* __restrict__ outp)
{
    __shared__ float sb[TT1 + 64];
    __shared__ float ssp[64];
    __shared__ double shk[64];
    int tid = threadIdx.x;
    int t0 = blockIdx.x * TT1;
    for (int i = tid; i < TT1 + TNO; i += 256) {
        int g = t0 + i;
        sb[i] = (g < T_TOT + 64) ? blo[g] : 0.f;
    }
    if (tid < 64) { ssp[tid] = spkk[tid]; shk[tid] = hkd[tid]; }
    __syncthreads();
    int t = t0 + tid;
    if (t >= T_TOT) return;
    float filt = 0.f;
    double a = 0.0;
    for (int m = 1; m <= TNO; ++m) {
        float b = sb[tid + TNO - m];             // spk[t-m]
        filt = fmaf(b, ssp[m - 1], filt);        // spk_kern[m-1]
        a += shk[m] * (double)b;                 // hist feedback (exact)
    }
    double p = 1.0 / (1.0 + exp(-(xd[t] + a)));
    outp[t] = filt;
    outp[T_TOT + t] = (float)p;
}

// ======================= launcher ===========================================
extern "C" void kernel_launch(void* const* d_in, const int* in_sizes, int n_in,
                              void* d_out, int out_size, void* d_ws, size_t ws_size,
                              hipStream_t stream)
{
    (void)in_sizes; (void)n_in; (void)out_size; (void)ws_size;
    const float* Se = (const float*)d_in[0];
    const float* Si = (const float*)d_in[1];
    const float* Ce = (const float*)d_in[2];
    const float* Ci = (const float*)d_in[3];
    const float* w1 = (const float*)d_in[4];
    const float* w4 = (const float*)d_in[5];
    const float* Wh = (const float*)d_in[6];
    const float* Th = (const float*)d_in[7];
    const float* Ws = (const float*)d_in[8];
    const float* Ta = (const float*)d_in[9];
    const float* u  = (const float*)d_in[10];

    char* w = (char*)d_ws;
    size_t off = 0;
    auto alloc = [&](size_t n) { size_t o = off; off += (n + 15) & ~(size_t)15; return o; };

    // G zone first: 32 MB, overlaid after conv1w with the scan/decision state
    size_t gzone = alloc((size_t)NCH * GROW * 4);          // 32,017,920 B
    float*  G     = (float*)(w + gzone);
    double* xd    = (double*)(w + gzone);                  // 1,600,000
    double* thrd  = (double*)(w + gzone + 1600000);        // 1,600,000
    float*  thr32 = (float*)(w + gzone + 3200000);         //   800,000
    float*  blo   = (float*)(w + gzone + 4000000);         //   800,512
    float*  bhi   = (float*)(w + gzone + 4800512);         //   800,512
    int*    dirty = (int*)(w + gzone + 5601024);           //     2,048 (NT2=391 ints)
    int*    utot  = (int*)(w + gzone + 5603072);           //        64
    int*    list  = (int*)(w + gzone + 5603200);           //   800,000
    double* afix  = (double*)(w + gzone + 6403200);        // 1,600,000 (8-aligned)
    int*    chead = (int*)(w + gzone + 8003200);           //   800,016
    int*    bits  = (int*)(w + gzone + 8803216);           //   800,000

    float*  syn     = (float*)(w + alloc((size_t)NCH * SROW * 4));   // 32 MB
    float*  out1    = (float*)(w + alloc((size_t)HIDN * T_TOT * 4)); // 16 MB
    float*  kern4   = (float*)(w + alloc((size_t)TM * HIDN * 4));
    float*  cmerged = (float*)(w + alloc((size_t)NCH * CW * 4));     // 222,720 B
    double* basisd  = (double*)(w + alloc((size_t)BNO * TM * 8));
    int*    ae      = (int*)(w + alloc(EE * 4));
    int*    ai      = (int*)(w + alloc(EI * 4));
    float*  hkpos   = (float*)(w + alloc(64 * 4));
    float*  hkneg   = (float*)(w + alloc(64 * 4));
    float*  spkk    = (float*)(w + alloc(64 * 4));
    float*  gtap    = (float*)(w + alloc(32 * 4));
    double* hkd     = (double*)(w + alloc(64 * 8));
    // total ws use ~81 MB

    k_setup<<<1, 1024, 0, stream>>>(Ce, Ci, Wh, Ws, Ta, ae, ai, hkpos, hkneg, spkk, gtap, hkd, basisd);
    int prepN = 2020 + NCH * CW + NCH * (PADL + PADR);
    k_prep<<<(prepN + 255) / 256, 256, 0, stream>>>(w1, w4, basisd, kern4, cmerged, syn);
    k_route<<<T_TOT / 64, 256, 0, stream>>>(Se, Si, ae, ai, syn);
    dim3 pg((GROW + 255) / 256, NCH);
    k_prefilt<<<pg, 256, 0, stream>>>(syn, gtap, G);
    k_conv1w<<<(T_TOT + C1TB - 1) / C1TB, 128, 0, stream>>>(G, syn, cmerged, out1);
    // ---- G dead from here; its zone now holds the decision state ----
    k_conv2<<<(T_TOT + TT1 - 1) / TT1, 256, 0, stream>>>(out1, kern4, Th, u, xd, thrd, thr32, blo, bhi);
    k_relax<<<NT2, 256, 0, stream>>>(thr32, hkpos, hkneg, blo, bhi, 0, dirty);
    k_relax<<<NT2, 256, 0, stream>>>(thr32, hkpos, hkneg, blo, bhi, 1, dirty);
    k_compact<<<NT2, 512, 0, stream>>>(blo, bhi, dirty, hkd, list, utot, afix);
    k_chainres<<<1, 1024, 0, stream>>>(list, afix, thrd, hkd, utot, chead, bits, blo, bhi);
    k_out<<<(T_TOT + TT1 - 1) / TT1, 256, 0, stream>>>(blo, spkk, hkd, xd, (float*)d_out);
}

// Round 12
// 1115.931 us; speedup vs baseline: 1.2034x; 1.2034x over previous
//
#include <hip/hip_runtime.h>
#include <math.h>

// ---- problem constants (from reference) ----
#define T_TOT  200000
#define EE     500
#define EI     100
#define SUBN   20
#define NCH    40      // 2*SUB
#define HIDN   20
#define BNO    34
#define TM     101     // basis kernel length
#define TNO    50      // history length / half kernel
#define HBNO   18
#define TT1    256     // t-tile for conv2/output kernels
#define EPSF   2e-5f   // sound margin for interval determinations
#define NTAP   58      // 34 G-taps + 24 edge-correction taps
#define CPT    12      // coefficient slots per tap (10 used, 48B stride)

// padded syn row: [64 zeros][T][256 zeros]
#define PADL   64
#define PADR   256
#define SROW   (PADL + T_TOT + PADR)   // 200320

// prefiltered G row: G_s[tau] at [s*GROW + tau+50], tau in [-50, T+61]
#define GROW   (T_TOT + 112)           // 200112

// conv1 LDS staging windows (per s, per 256-t block)
#define GW     355     // G: local i = tloc + 3b (+64 partner)
#define SW     380     // syn: local i = tloc+mi | tloc+mi+101 (+64 partner)
#define CW     (2 * NTAP * CPT)   // 1392 coefficient floats per s

// relax tiling
#define RTILE  512
#define RHALO  64
#define RRND   4
#define NT2    ((T_TOT + RTILE - 1) / RTILE)   // 391

// ======================= setup: assignments, small kernels, basis ============
__global__ void k_setup(const float* __restrict__ Ce, const float* __restrict__ Ci,
                        const float* __restrict__ Wh, const float* __restrict__ Wspk,
                        const float* __restrict__ Tau,
                        int* __restrict__ ae, int* __restrict__ ai,
                        float* __restrict__ hkpos, float* __restrict__ hkneg,
                        float* __restrict__ spkk, float* __restrict__ gtap,
                        double* __restrict__ hkd, double* __restrict__ basisd)
{
    int tid = threadIdx.x;  // block 1024
    if (tid < EE) {
        int a = 0;
        for (int s = 0; s < SUBN; ++s) if (Ce[s * EE + tid] > 0.5f) a = s;
        ae[tid] = a;
    } else if (tid < EE + EI) {
        int e = tid - EE; int a = 0;
        for (int s = 0; s < SUBN; ++s) if (Ci[s * EI + e] > 0.5f) a = s;
        ai[e] = a;
    } else if (tid < 664) {
        // hk_r[j] = hist_kern[TNO - j], j in [1,TNO]; zero-fill rest of 64
        int j = tid - 600;
        double hk = 0.0;
        if (j >= 1 && j <= TNO) {
            int i = TNO - j;
            for (int b = 0; b < HBNO; ++b) {
                double d = (double)i - 3.0 * (double)b;
                hk += (double)Wh[b] * exp(-d * d / 3.0);
            }
        }
        hkd[j] = hk;
        hkpos[j] = (float)fmax(hk, 0.0);
        hkneg[j] = (float)fmin(hk, 0.0);
    } else if (tid < 728) {
        int m = tid - 664; float v = 0.f;
        if (m < TNO) {
            double tau2 = (double)Tau[0] * (double)Tau[0];
            double tt = (double)m / tau2;
            v = (float)(tt * exp(-tt) * (double)Wspk[0] * (double)Wspk[0]);
        }
        spkk[m] = v;
    } else if (tid < 753) {
        int j = tid - 740;                       // j in [-12, 12]
        gtap[tid - 728] = (float)exp(-(double)(j * j) / 3.0);
    }
    // Gaussian basis table (fp64) for kern4 construction
    for (int idx = tid; idx < BNO * TM; idx += blockDim.x) {
        int b = idx / TM, k = idx % TM;
        double d = (double)k - 3.0 * (double)b;
        basisd[idx] = exp(-d * d / 3.0);
    }
}

// ======================= prep: kern4, wave-packed coefficients, pads =========
// cmerged layout: [s][hgrp(2)][tap(58)][12]; slot f<10 -> h = hgrp*10+f.
// tap<34: w1[h,s,tap]; tap>=34 (mi=tap-34): NEGATED edge-correction coef.
__global__ void k_prep(const float* __restrict__ w1, const float* __restrict__ w4,
                       const double* __restrict__ basisd,
                       float* __restrict__ kern4, float* __restrict__ cmerged,
                       float* __restrict__ syn)
{
    int idx = blockIdx.x * 256 + threadIdx.x;
    if (idx < HIDN * TM) {
        int h = idx % HIDN, k = idx / HIDN;
        double acc = 0.0;
        for (int b = 0; b < BNO; ++b) acc += (double)w4[h * BNO + b] * basisd[b * TM + k];
        kern4[k * HIDN + h] = (float)acc;        // [k][h] layout
    } else if (idx < 2020 + NCH * CW) {
        int j = idx - 2020;
        int f = j % CPT, tap = (j / CPT) % NTAP, hg = (j / (CPT * NTAP)) & 1, s = j / CW;
        float val = 0.f;
        if (f < 10) {
            int h = hg * 10 + f;
            if (tap < BNO) {
                val = w1[(h * NCH + s) * BNO + tap];
            } else {
                int mi = tap - BNO;
                int m = (mi < 12) ? (mi - 62) : (mi + 39);
                double acc = 0.0;
                for (int b = 0; b < BNO; ++b) {
                    int jj = m + 50 - 3 * b;     // Gaussian tap our G includes
                    if (jj >= -12 && jj <= 12)
                        acc += (double)w1[(h * NCH + s) * BNO + b] * exp(-(double)(jj * jj) / 3.0);
                }
                val = -(float)acc;               // pre-negated
            }
        }
        cmerged[j] = val;
    } else if (idx < 2020 + NCH * CW + NCH * (PADL + PADR)) {
        int j = idx - (2020 + NCH * CW);
        int r = j / (PADL + PADR), c = j % (PADL + PADR);
        int off = (c < PADL) ? c : (PADL + T_TOT + (c - PADL));
        syn[(size_t)r * SROW + off] = 0.f;
    }
}

// ======================= synapse -> subunit routing (float4, 2-way ILP) ======
__global__ __launch_bounds__(256) void k_route(const float* __restrict__ Se,
                                               const float* __restrict__ Si,
                                               const int* __restrict__ ae,
                                               const int* __restrict__ ai,
                                               float* __restrict__ syn)
{
    __shared__ float acc[NCH * 64];
    __shared__ int sae[EE];
    __shared__ int sai[EI];
    int tid = threadIdx.x;
    for (int i = tid; i < NCH * 64; i += 256) acc[i] = 0.f;
    for (int i = tid; i < EE; i += 256) sae[i] = ae[i];
    for (int i = tid; i < EI; i += 256) sai[i] = ai[i];
    __syncthreads();
    int t0 = blockIdx.x * 64;              // T divisible by 64
    int lane = tid & 63, grp = tid >> 6;
    for (int ec = 0; ec < 2; ++ec) {
        int ev = ec * 64 + lane;           // float4 index; 125 cover 500 floats
        if (ev < EE / 4) {
            int e = 4 * ev;
            int a0 = sae[e], a1 = sae[e + 1], a2 = sae[e + 2], a3 = sae[e + 3];
            for (int ts = grp; ts < 64; ts += 8) {
                float4 v1 = *(const float4*)(Se + (size_t)(t0 + ts) * EE + e);
                float4 v2 = *(const float4*)(Se + (size_t)(t0 + ts + 4) * EE + e);
                if (v1.x != 0.f) atomicAdd(&acc[a0 * 64 + ts], v1.x);
                if (v1.y != 0.f) atomicAdd(&acc[a1 * 64 + ts], v1.y);
                if (v1.z != 0.f) atomicAdd(&acc[a2 * 64 + ts], v1.z);
                if (v1.w != 0.f) atomicAdd(&acc[a3 * 64 + ts], v1.w);
                if (v2.x != 0.f) atomicAdd(&acc[a0 * 64 + ts + 4], v2.x);
                if (v2.y != 0.f) atomicAdd(&acc[a1 * 64 + ts + 4], v2.y);
                if (v2.z != 0.f) atomicAdd(&acc[a2 * 64 + ts + 4], v2.z);
                if (v2.w != 0.f) atomicAdd(&acc[a3 * 64 + ts + 4], v2.w);
            }
        }
    }
    {
        int ev = lane;                     // 25 cover 100 floats
        if (ev < EI / 4) {
            int e = 4 * ev;
            int a0 = sai[e] + SUBN, a1 = sai[e + 1] + SUBN, a2 = sai[e + 2] + SUBN, a3 = sai[e + 3] + SUBN;
            for (int ts = grp; ts < 64; ts += 8) {
                float4 v1 = *(const float4*)(Si + (size_t)(t0 + ts) * EI + e);
                float4 v2 = *(const float4*)(Si + (size_t)(t0 + ts + 4) * EI + e);
                if (v1.x != 0.f) atomicAdd(&acc[a0 * 64 + ts], v1.x);
                if (v1.y != 0.f) atomicAdd(&acc[a1 * 64 + ts], v1.y);
                if (v1.z != 0.f) atomicAdd(&acc[a2 * 64 + ts], v1.z);
                if (v1.w != 0.f) atomicAdd(&acc[a3 * 64 + ts], v1.w);
                if (v2.x != 0.f) atomicAdd(&acc[a0 * 64 + ts + 4], v2.x);
                if (v2.y != 0.f) atomicAdd(&acc[a1 * 64 + ts + 4], v2.y);
                if (v2.z != 0.f) atomicAdd(&acc[a2 * 64 + ts + 4], v2.z);
                if (v2.w != 0.f) atomicAdd(&acc[a3 * 64 + ts + 4], v2.w);
            }
        }
    }
    __syncthreads();
    for (int i = tid; i < NCH * 64; i += 256) {
        int s = i >> 6, ts = i & 63;
        syn[(size_t)s * SROW + PADL + t0 + ts] = acc[i];
    }
}

// ======================= Gaussian prefilter: G_s = g (*) syn_s ===============
__global__ __launch_bounds__(256) void k_prefilt(const float* __restrict__ syn,
                                                 const float* __restrict__ gtap,
                                                 float* __restrict__ G)
{
    int gi = blockIdx.x * 256 + threadIdx.x;     // gridDim.y = s
    if (gi >= GROW) return;
    const float* sp = syn + (size_t)blockIdx.y * SROW + PADL + (gi - 50);
    double a = 0.0;
#pragma unroll
    for (int j = -12; j <= 12; ++j)
        a += (double)gtap[j + 12] * (double)sp[j];
    G[(size_t)blockIdx.y * GROW + gi] = (float)a;
}

// 20 FMAs per tap: coefficient 10-vector (c0,c1,c2) x data pair (v0,v1)
#define FMA10(c0, c1, c2, v0, v1)                                              \
    acc[0][0] = fmaf(c0.x, v0, acc[0][0]); acc[0][1] = fmaf(c0.x, v1, acc[0][1]); \
    acc[1][0] = fmaf(c0.y, v0, acc[1][0]); acc[1][1] = fmaf(c0.y, v1, acc[1][1]); \
    acc[2][0] = fmaf(c0.z, v0, acc[2][0]); acc[2][1] = fmaf(c0.z, v1, acc[2][1]); \
    acc[3][0] = fmaf(c0.w, v0, acc[3][0]); acc[3][1] = fmaf(c0.w, v1, acc[3][1]); \
    acc[4][0] = fmaf(c1.x, v0, acc[4][0]); acc[4][1] = fmaf(c1.x, v1, acc[4][1]); \
    acc[5][0] = fmaf(c1.y, v0, acc[5][0]); acc[5][1] = fmaf(c1.y, v1, acc[5][1]); \
    acc[6][0] = fmaf(c1.z, v0, acc[6][0]); acc[6][1] = fmaf(c1.z, v1, acc[6][1]); \
    acc[7][0] = fmaf(c1.w, v0, acc[7][0]); acc[7][1] = fmaf(c1.w, v1, acc[7][1]); \
    acc[8][0] = fmaf(c2.x, v0, acc[8][0]); acc[8][1] = fmaf(c2.x, v1, acc[8][1]); \
    acc[9][0] = fmaf(c2.y, v0, acc[9][0]); acc[9][1] = fmaf(c2.y, v1, acc[9][1]);

// ======================= conv1: R9 + conflict-free stride-64 data ============
// Block = 4 waves; wave w: h-group (w&1)*10..+9, t-half (w>>1)*128; lane owns
// t = tloc and tloc+64 (stride-1 pair 256B apart -> ds_read2st64_b32,
// conflict-free). Coefficients staged in LDS (double-buffered), read as
// wave-uniform b128/b64 broadcasts (~6 cyc each). FMA order per (h,t):
// s asc, tap asc -- identical to R4-R11 -> bitwise-identical out1.
__global__ __launch_bounds__(256) void k_conv1w(const float* __restrict__ G,
                                                const float* __restrict__ syn,
                                                const float* __restrict__ cmerged,
                                                float* __restrict__ out1)
{
    __shared__ __align__(16) float sg[2][GW];
    __shared__ __align__(16) float ss[2][SW];
    __shared__ __align__(16) float sc[2][CW];
    int tid = threadIdx.x;
    int wv = tid >> 6, lane = tid & 63;
    int hg = wv & 1;
    int tsub = wv >> 1;
    int tloc = tsub * 128 + lane;            // owns tloc and tloc+64
    int t0 = blockIdx.x * 256;

    {   // stage s=0 into buffer 0
        const float* Gp = G + t0;
        const float* sp = syn + PADL + t0 - 62;
        for (int i = tid; i < GW; i += 256) sg[0][i] = (t0 + i < GROW) ? Gp[i] : 0.f;
        for (int i = tid; i < SW; i += 256) ss[0][i] = sp[i];
        for (int i = tid; i < CW; i += 256) sc[0][i] = cmerged[i];
    }

    float acc[10][2];
#pragma unroll
    for (int hh = 0; hh < 10; ++hh) { acc[hh][0] = 0.f; acc[hh][1] = 0.f; }

    for (int s = 0; s < NCH; ++s) {
        __syncthreads();                     // buf[s&1] staged & prior reads done
        int cb = s & 1, nb = cb ^ 1;
        if (s + 1 < NCH) {                   // prefetch next s
            const float* Gp = G + (size_t)(s + 1) * GROW + t0;
            const float* sp = syn + (size_t)(s + 1) * SROW + PADL + t0 - 62;
            const float* cp = cmerged + (size_t)(s + 1) * CW;
            for (int i = tid; i < GW; i += 256) sg[nb][i] = (t0 + i < GROW) ? Gp[i] : 0.f;
            for (int i = tid; i < SW; i += 256) ss[nb][i] = sp[i];
            for (int i = tid; i < CW; i += 256) sc[nb][i] = cp[i];
        }
        const float* sgc = sg[cb] + tloc;
        const float* ssc = ss[cb] + tloc;
        const float* cc = sc[cb] + hg * (NTAP * CPT);
#pragma unroll 2
        for (int b = 0; b < BNO; ++b) {
            float v0 = sgc[3 * b], v1 = sgc[3 * b + 64];     // ds_read2st64_b32
            const float* cp = cc + b * CPT;                  // 48B stride, 16B-aligned
            float4 c0 = *(const float4*)cp;                  // wave-uniform broadcasts
            float4 c1 = *(const float4*)(cp + 4);
            float2 c2 = *(const float2*)(cp + 8);
            FMA10(c0, c1, c2, v0, v1)
        }
#pragma unroll 2
        for (int mi = 0; mi < 12; ++mi) {
            float v0 = ssc[mi], v1 = ssc[mi + 64];           // syn_s[t + mi - 62]
            const float* cp = cc + (BNO + mi) * CPT;
            float4 c0 = *(const float4*)cp;
            float4 c1 = *(const float4*)(cp + 4);
            float2 c2 = *(const float2*)(cp + 8);
            FMA10(c0, c1, c2, v0, v1)
        }
#pragma unroll 2
        for (int mi = 12; mi < 24; ++mi) {
            float v0 = ssc[mi + 101], v1 = ssc[mi + 165];    // syn_s[t + mi + 39]
            const float* cp = cc + (BNO + mi) * CPT;
            float4 c0 = *(const float4*)cp;
            float4 c1 = *(const float4*)(cp + 4);
            float2 c2 = *(const float2*)(cp + 8);
            FMA10(c0, c1, c2, v0, v1)
        }
    }
    int t1 = t0 + tloc, t2 = t1 + 64;
#pragma unroll
    for (int hh = 0; hh < 10; ++hh) {
        int h = hg * 10 + hh;
        float o0 = acc[hh][0], o1 = acc[hh][1];
        if (t1 < T_TOT) out1[(size_t)h * T_TOT + t1] = (o0 > 0.f) ? o0 : 0.01f * o0;
        if (t2 < T_TOT) out1[(size_t)h * T_TOT + t2] = (o1 > 0.f) ? o1 : 0.01f * o1;
    }
}

// ======================= conv2 (fp64 acc) + logit threshold + state init =====
__global__ __launch_bounds__(256) void k_conv2(const float* __restrict__ out1,
                                               const float* __restrict__ kern4,
                                               const float* __restrict__ Theta,
                                               const float* __restrict__ u,
                                               double* __restrict__ xd,
                                               double* __restrict__ thrd,
                                               float* __restrict__ thr32,
                                               float* __restrict__ blo,
                                               float* __restrict__ bhi)
{
    __shared__ float s1[HIDN * (TT1 + 100)];    // 28,480 B
    int tid = threadIdx.x;
    int t0 = blockIdx.x * TT1;
    for (int i = tid; i < HIDN * (TT1 + 100); i += 256) {
        int h = i / (TT1 + 100), x = i % (TT1 + 100);
        int g = t0 + x - TNO;
        s1[i] = (g >= 0 && g < T_TOT) ? out1[(size_t)h * T_TOT + g] : 0.f;
    }
    __syncthreads();
    int t = t0 + tid;
    if (t >= T_TOT) return;
    double acc = 0.0;
    for (int k = 0; k < TM; ++k) {
        const float* kp = kern4 + k * HIDN;
#pragma unroll
        for (int h = 0; h < HIDN; ++h)
            acc = fma((double)s1[h * (TT1 + 100) + tid + k], (double)kp[h], acc);
    }
    double x = acc + (double)Theta[0];
    double uu = (double)u[t];
    // spike  <=>  u < sigmoid(x + a)  <=>  a > logit(u) - x
    double th = (log(uu) - log1p(-uu)) - x;     // u==0 -> -inf -> always spike (correct)
    xd[t] = x; thrd[t] = th; thr32[t] = (float)th;
    // interval init (index = t + TNO): unknown everywhere, pads zero
    blo[t + TNO] = 0.f;
    bhi[t + TNO] = 1.f;
    if (t < TNO) { blo[t] = 0.f; bhi[t] = 0.f; }
    if (t < 14)  { blo[T_TOT + TNO + t] = 0.f; bhi[T_TOT + TNO + t] = 0.f; }
}

// ======================= sound interval relaxation (+ optional dirty) ========
__global__ __launch_bounds__(256) void k_relax(const float* __restrict__ thr32,
                                               const float* __restrict__ hkpos,
                                               const float* __restrict__ hkneg,
                                               float* __restrict__ blo,
                                               float* __restrict__ bhi,
                                               int wd, int* __restrict__ dirty)
{
    __shared__ float slo[RTILE + RHALO], shi[RTILE + RHALO];
    __shared__ float sth[RTILE + RHALO];
    __shared__ float shp[64], shn[64];
    int tid = threadIdx.x;
    int t0 = blockIdx.x * RTILE;
    for (int i = tid; i < RTILE + RHALO; i += 256) {
        int t = t0 - RHALO + i;
        int g = t + TNO;
        bool ok = (g >= 0 && g < T_TOT + 64);
        slo[i] = ok ? blo[g] : 0.f;
        shi[i] = ok ? bhi[g] : 0.f;
        sth[i] = (t >= 0 && t < T_TOT) ? thr32[t] : 0.f;
    }
    if (tid < 64) { shp[tid] = hkpos[tid]; shn[tid] = hkneg[tid]; }
    __syncthreads();
    for (int r = 0; r < RRND; ++r) {
        for (int i = tid; i < RTILE + RHALO; i += 256) {
            if (i < TNO) continue;                   // needs 50 left neighbors in LDS
            float l = slo[i], h = shi[i];
            if (l == h) continue;
            float lo = 0.f, hi = 0.f;
            for (int j = 1; j <= TNO; ++j) {
                float bl = slo[i - j], bh = shi[i - j];
                float hp = shp[j], hn = shn[j];
                lo = fmaf(hp, bl, lo); lo = fmaf(hn, bh, lo);
                hi = fmaf(hp, bh, hi); hi = fmaf(hn, bl, hi);
            }
            float th = sth[i];
            if (lo > th + EPSF)      slo[i] = 1.f;   // determined spike
            else if (hi < th - EPSF) shi[i] = 0.f;   // determined no-spike
        }
        __syncthreads();
    }
    for (int i = tid; i < RTILE; i += 256) {         // write back interior only
        int t = t0 + i;
        if (t < T_TOT) {
            blo[t + TNO] = slo[RHALO + i];
            bhi[t + TNO] = shi[RHALO + i];
        }
    }
    if (wd) {                                        // final launch: per-tile counts
        int i1 = tid, i2 = tid + 256;
        int u1 = (t0 + i1 < T_TOT) && (slo[RHALO + i1] != shi[RHALO + i1]);
        int u2 = (t0 + i2 < T_TOT) && (slo[RHALO + i2] != shi[RHALO + i2]);
        int c = __syncthreads_count(u1);
        c += __syncthreads_count(u2);
        if (tid == 0) dirty[blockIdx.x] = c;
    }
}

// ======================= compact unknowns + known-history dots (fp64) ========
__global__ __launch_bounds__(512) void k_compact(const float* __restrict__ blo,
                                                 const float* __restrict__ bhi,
                                                 const int* __restrict__ dirty,
                                                 const double* __restrict__ hkd,
                                                 int* __restrict__ list,
                                                 int* __restrict__ utot,
                                                 double* __restrict__ afix)
{
    __shared__ int wsum[8];
    __shared__ int sd[NT2];
    __shared__ int sbase;
    int tid = threadIdx.x;
    for (int i = tid; i < NT2; i += 512) sd[i] = dirty[i];
    int t = blockIdx.x * 512 + tid;
    int unk = (t < T_TOT) && (blo[t + TNO] != bhi[t + TNO]);
    unsigned long long m = __ballot(unk);
    int lane = tid & 63, wv = tid >> 6;
    int lr = __popcll(m & ((1ull << lane) - 1ull));
    if (lane == 0) wsum[wv] = __popcll(m);
    __syncthreads();
    if (tid == 0) {
        int b = 0;
        for (int k = 0; k < (int)blockIdx.x; ++k) b += sd[k];
        sbase = b;
        if (blockIdx.x == 0) {
            int tot = 0;
            for (int k = 0; k < NT2; ++k) tot += sd[k];
            utot[0] = tot;
        }
        int r = 0;
        for (int k = 0; k < 8; ++k) { int c = wsum[k]; wsum[k] = r; r += c; }
    }
    __syncthreads();
    if (unk) {
        int pos = sbase + wsum[wv] + lr;
        list[pos] = t;
        double a = 0.0;
        for (int j = 1; j <= TNO; ++j)
            a += hkd[j] * (double)blo[t - j + TNO];   // unknowns read as 0
        afix[pos] = a;
    }
}

// ======================= chain split + exact resolve (single block) ==========
__global__ __launch_bounds__(1024) void k_chainres(const int* __restrict__ list,
                                                   const double* __restrict__ afix,
                                                   const double* __restrict__ thrd,
                                                   const double* __restrict__ hkd,
                                                   const int* __restrict__ utot,
                                                   int* __restrict__ chead,
                                                   int* __restrict__ bits,
                                                   float* __restrict__ blo,
                                                   float* __restrict__ bhi)
{
    __shared__ double shk[64];
    __shared__ int wcnt[16];
    __shared__ int base_s;
    int tid = threadIdx.x, lane = tid & 63, wv = tid >> 6;
    if (tid < 64) shk[tid] = (tid >= 1 && tid <= TNO) ? hkd[tid] : 0.0;
    if (tid == 0) base_s = 0;
    int U = utot[0];
    __syncthreads();
    for (int b0 = 0; b0 < U; b0 += 1024) {
        int i = b0 + tid;
        int head = 0;
        if (i < U) head = (i == 0) || (list[i] - list[i - 1] > TNO);
        unsigned long long m = __ballot(head);
        int pre = __popcll(m & ((1ull << lane) - 1ull));
        if (lane == 0) wcnt[wv] = __popcll(m);
        __syncthreads();
        int wbase = 0;
        for (int k = 0; k < wv; ++k) wbase += wcnt[k];
        int tot = 0;
        for (int k = 0; k < 16; ++k) tot += wcnt[k];
        if (head) chead[base_s + wbase + pre] = i;
        __syncthreads();
        if (tid == 0) base_s += tot;
        __syncthreads();
    }
    int nch = base_s;
    for (int c = tid; c < nch; c += 1024) {
        int i0 = chead[c];
        int i1 = (c + 1 < nch) ? chead[c + 1] : U;
        for (int i = i0; i < i1; ++i) {
            int t = list[i];
            double a = afix[i];
            for (int k = i - 1; k >= i0; --k) {   // unknown predecessors (same chain)
                int dt = t - list[k];
                if (dt > TNO) break;
                if (bits[k]) a += shk[dt];
            }
            int sb = (a > thrd[t]) ? 1 : 0;
            bits[i] = sb;
            float f = (float)sb;
            blo[t + TNO] = f;
            bhi[t + TNO] = f;
        }
    }
}

// ======================= outputs: spk_filt + prob_out ========================
__global__ __launch_bounds__(256) void k_out(const float* __restrict__ blo,
                                             const float* __restrict__ spkk,
                                             const double* __restrict__ hkd,
                                             const double* __restrict__ xd,
                                             float* __restrict__ outp)
{
    __shared__ float sb[TT1 + 64];
    __shared__ float ssp[64];
    __shared__ double shk[64];
    int tid = threadIdx.x;
    int t0 = blockIdx.x * TT1;
    for (int i = tid; i < TT1 + TNO; i += 256) {
        int g = t0 + i;
        sb[i] = (g < T_TOT + 64) ? blo[g] : 0.f;
    }
    if (tid < 64) { ssp[tid] = spkk[tid]; shk[tid] = hkd[tid]; }
    __syncthreads();
    int t = t0 + tid;
    if (t >= T_TOT) return;
    float filt = 0.f;
    double a = 0.0;
    for (int m = 1; m <= TNO; ++m) {
        float b = sb[tid + TNO - m];             // spk[t-m]
        filt = fmaf(b, ssp[m - 1], filt);        // spk_kern[m-1]
        a += shk[m] * (double)b;                 // hist feedback (exact)
    }
    double p = 1.0 / (1.0 + exp(-(xd[t] + a)));
    outp[t] = filt;
    outp[T_TOT + t] = (float)p;
}

// ======================= launcher ===========================================
extern "C" void kernel_launch(void* const* d_in, const int* in_sizes, int n_in,
                              void* d_out, int out_size, void* d_ws, size_t ws_size,
                              hipStream_t stream)
{
    (void)in_sizes; (void)n_in; (void)out_size; (void)ws_size;
    const float* Se = (const float*)d_in[0];
    const float* Si = (const float*)d_in[1];
    const float* Ce = (const float*)d_in[2];
    const float* Ci = (const float*)d_in[3];
    const float* w1 = (const float*)d_in[4];
    const float* w4 = (const float*)d_in[5];
    const float* Wh = (const float*)d_in[6];
    const float* Th = (const float*)d_in[7];
    const float* Ws = (const float*)d_in[8];
    const float* Ta = (const float*)d_in[9];
    const float* u  = (const float*)d_in[10];

    char* w = (char*)d_ws;
    size_t off = 0;
    auto alloc = [&](size_t n) { size_t o = off; off += (n + 15) & ~(size_t)15; return o; };

    // G zone first: 32 MB, overlaid after conv1w with the scan/decision state
    size_t gzone = alloc((size_t)NCH * GROW * 4);          // 32,017,920 B
    float*  G     = (float*)(w + gzone);
    double* xd    = (double*)(w + gzone);                  // 1,600,000
    double* thrd  = (double*)(w + gzone + 1600000);        // 1,600,000
    float*  thr32 = (float*)(w + gzone + 3200000);         //   800,000
    float*  blo   = (float*)(w + gzone + 4000000);         //   800,512
    float*  bhi   = (float*)(w + gzone + 4800512);         //   800,512
    int*    dirty = (int*)(w + gzone + 5601024);           //     2,048 (NT2=391 ints)
    int*    utot  = (int*)(w + gzone + 5603072);           //        64
    int*    list  = (int*)(w + gzone + 5603200);           //   800,000
    double* afix  = (double*)(w + gzone + 6403200);        // 1,600,000 (8-aligned)
    int*    chead = (int*)(w + gzone + 8003200);           //   800,016
    int*    bits  = (int*)(w + gzone + 8803216);           //   800,000

    float*  syn     = (float*)(w + alloc((size_t)NCH * SROW * 4));   // 32 MB
    float*  out1    = (float*)(w + alloc((size_t)HIDN * T_TOT * 4)); // 16 MB
    float*  kern4   = (float*)(w + alloc((size_t)TM * HIDN * 4));
    float*  cmerged = (float*)(w + alloc((size_t)NCH * CW * 4));     // 222,720 B
    double* basisd  = (double*)(w + alloc((size_t)BNO * TM * 8));
    int*    ae      = (int*)(w + alloc(EE * 4));
    int*    ai      = (int*)(w + alloc(EI * 4));
    float*  hkpos   = (float*)(w + alloc(64 * 4));
    float*  hkneg   = (float*)(w + alloc(64 * 4));
    float*  spkk    = (float*)(w + alloc(64 * 4));
    float*  gtap    = (float*)(w + alloc(32 * 4));
    double* hkd     = (double*)(w + alloc(64 * 8));
    // total ws use ~81 MB

    k_setup<<<1, 1024, 0, stream>>>(Ce, Ci, Wh, Ws, Ta, ae, ai, hkpos, hkneg, spkk, gtap, hkd, basisd);
    int prepN = 2020 + NCH * CW + NCH * (PADL + PADR);
    k_prep<<<(prepN + 255) / 256, 256, 0, stream>>>(w1, w4, basisd, kern4, cmerged, syn);
    k_route<<<T_TOT / 64, 256, 0, stream>>>(Se, Si, ae, ai, syn);
    dim3 pg((GROW + 255) / 256, NCH);
    k_prefilt<<<pg, 256, 0, stream>>>(syn, gtap, G);
    k_conv1w<<<(T_TOT + 255) / 256, 256, 0, stream>>>(G, syn, cmerged, out1);
    // ---- G dead from here; its zone now holds the decision state ----
    k_conv2<<<(T_TOT + TT1 - 1) / TT1, 256, 0, stream>>>(out1, kern4, Th, u, xd, thrd, thr32, blo, bhi);
    k_relax<<<NT2, 256, 0, stream>>>(thr32, hkpos, hkneg, blo, bhi, 0, dirty);
    k_relax<<<NT2, 256, 0, stream>>>(thr32, hkpos, hkneg, blo, bhi, 1, dirty);
    k_compact<<<NT2, 512, 0, stream>>>(blo, bhi, dirty, hkd, list, utot, afix);
    k_chainres<<<1, 1024, 0, stream>>>(list, afix, thrd, hkd, utot, chead, bits, blo, bhi);
    k_out<<<(T_TOT + TT1 - 1) / TT1, 256, 0, stream>>>(blo, spkk, hkd, xd, (float*)d_out);
}